// Round 7
// baseline (1958.974 us; speedup 1.0000x reference)
//
#include <hip/hip_runtime.h>

#define T_LEN 2048
#define DH 256
#define NCHUNK (T_LEN / 16)

typedef short short8 __attribute__((ext_vector_type(8)));
typedef float f32x4 __attribute__((ext_vector_type(4)));

__device__ __forceinline__ unsigned short f2bf(float f) {
  unsigned u = __builtin_bit_cast(unsigned, f);
  u += 0x7fffu + ((u >> 16) & 1u);   // round-to-nearest-even
  return (unsigned short)(u >> 16);
}

// Raw WG barrier: flush this wave's LDS ops, barrier, fence the scheduler.
// Deliberately does NOT drain vmcnt — prefetch loads / chunk stores stay in
// flight across intervals (no cross-wave hazard goes through global memory).
#define WG_BARRIER() do {                                   \
  __builtin_amdgcn_sched_barrier(0);                        \
  asm volatile("s_waitcnt lgkmcnt(0)" ::: "memory");        \
  __builtin_amdgcn_s_barrier();                             \
  __builtin_amdgcn_sched_barrier(0);                        \
} while (0)

// ---------------------------------------------------------------------------
// Phase 1: out = x @ W_in + b_in + b_h (b_h folded). Grid 512 x 256 thr.
// MFMA 16x16x32 bf16. A[m][k]: m=lane&15, k=(lane>>4)*8+j; B same k, c=lane&15;
// D: c=lane&15, m=(lane>>4)*4+r.
// ---------------------------------------------------------------------------
__global__ __launch_bounds__(256, 1) void xproj_gemm(
    const float* __restrict__ x, const float* __restrict__ W_in,
    const float* __restrict__ b_in, const float* __restrict__ b_h,
    float* __restrict__ out) {
  const int tid  = threadIdx.x;
  const int lane = tid & 63;
  const int w    = tid >> 6;
  const int l15  = lane & 15;
  const int lg   = lane >> 4;
  const int koff = lg * 8;
  const int m0   = blockIdx.x * 128;

  short8 Bf[4][8];
#pragma unroll
  for (int n = 0; n < 4; ++n) {
    const int c = 64 * w + 16 * n + l15;
#pragma unroll
    for (int kk = 0; kk < 8; ++kk) {
      short8 bf;
#pragma unroll
      for (int j = 0; j < 8; ++j)
        bf[j] = (short)f2bf(W_in[(32 * kk + koff + j) * DH + c]);
      Bf[n][kk] = bf;
    }
  }
  float bin[4];
#pragma unroll
  for (int n = 0; n < 4; ++n) {
    const int c = 64 * w + 16 * n + l15;
    bin[n] = b_in[c] + b_h[c];
  }

  for (int slab = 0; slab < 8; ++slab) {
    const float* xr = x + (size_t)(m0 + slab * 16 + l15) * DH;
    short8 A[8];
#pragma unroll
    for (int kk = 0; kk < 8; ++kk) {
      f32x4 v0 = *(const f32x4*)(xr + 32 * kk + koff);
      f32x4 v1 = *(const f32x4*)(xr + 32 * kk + koff + 4);
      short8 a;
      a[0] = f2bf(v0[0]); a[1] = f2bf(v0[1]); a[2] = f2bf(v0[2]); a[3] = f2bf(v0[3]);
      a[4] = f2bf(v1[0]); a[5] = f2bf(v1[1]); a[6] = f2bf(v1[2]); a[7] = f2bf(v1[3]);
      A[kk] = a;
    }
    f32x4 acc[4];
#pragma unroll
    for (int n = 0; n < 4; ++n) acc[n] = (f32x4){0.f, 0.f, 0.f, 0.f};
#pragma unroll
    for (int kk = 0; kk < 8; ++kk)
#pragma unroll
      for (int n = 0; n < 4; ++n)
        acc[n] = __builtin_amdgcn_mfma_f32_16x16x32_bf16(A[kk], Bf[n][kk], acc[n], 0, 0, 0);
#pragma unroll
    for (int n = 0; n < 4; ++n) {
      const int c = 64 * w + 16 * n + l15;
#pragma unroll
      for (int r = 0; r < 4; ++r)
        out[(size_t)(m0 + slab * 16 + lg * 4 + r) * DH + c] = acc[n][r] + bin[n];
    }
  }
}

// ---------------------------------------------------------------------------
// Phase 2: serial scan, TWO batches per WG, staggered by one barrier interval.
// Grid 16 x 512 thr (8 waves). Wave w owns cols [32w, 32w+32); Bf shared by
// both batches. Interval (barrier-to-barrier) for computing batch C while
// batch O is in its LDS-turnaround:
//   1. issue xb read for C (consumed at this interval's end)
//   2. issue A-frag reads for O (consumed NEXT interval -> zero MFMA wait)
//   3. O's chunk-boundary work (publish xpb / prefetch / dump xout) if due
//   4. 16 MFMAs for C (inputs read LAST interval -> no lgkm wait)
//   5. epilogue C: +xb, relu, write hb_C (bf16) + xout_C
//   6. WG_BARRIER
// Every LDS write->cross-wave-read pair is separated by >=1 barrier; h is
// single-buffered per batch (read-complete forced by pre-barrier lgkmcnt(0),
// overwrite is post-barrier).
// ---------------------------------------------------------------------------
__global__ __launch_bounds__(512, 2) void rnn_scan(
    const float* __restrict__ h0, const float* __restrict__ W_h,
    float* __restrict__ out) {
  __shared__ __align__(16) unsigned short hb_A[DH];
  __shared__ __align__(16) unsigned short hb_B[DH];
  __shared__ __align__(16) float xpb_A[2][16 * DH];
  __shared__ __align__(16) float xpb_B[2][16 * DH];
  __shared__ __align__(16) float xout_A[16 * DH];
  __shared__ __align__(16) float xout_B[16 * DH];

  const int tid  = threadIdx.x;
  const int lane = tid & 63;
  const int w    = tid >> 6;         // 0..7
  const int l15  = lane & 15;
  const int lg   = lane >> 4;
  const int koff = lg * 8;
  const int bA   = blockIdx.x * 2;
  const int bB   = bA + 1;
  float* outb_A = out + (size_t)bA * T_LEN * DH;
  float* outb_B = out + (size_t)bB * T_LEN * DH;

  // Issue chunk-0 x_proj loads first (fly under the W_h fragment load).
  f32x4 st_A[2], st_B[2];
#pragma unroll
  for (int i = 0; i < 2; ++i) {
    st_A[i] = *(const f32x4*)(outb_A + i * 2048 + tid * 4);
    st_B[i] = *(const f32x4*)(outb_B + i * 2048 + tid * 4);
  }

  // W_h bf16 fragments: wave w owns cols [32w, 32w+32) as 2 16-col tiles.
  short8 Bf[2][8];
#pragma unroll
  for (int n = 0; n < 2; ++n) {
    const int c = 32 * w + 16 * n + l15;
#pragma unroll
    for (int kk = 0; kk < 8; ++kk) {
      short8 bf;
#pragma unroll
      for (int j = 0; j < 8; ++j)
        bf[j] = (short)f2bf(W_h[(32 * kk + koff + j) * DH + c]);
      Bf[n][kk] = bf;
    }
  }

  if (tid < DH) hb_A[tid] = f2bf(h0[bA * DH + tid]);
  else          hb_B[tid - DH] = f2bf(h0[bB * DH + (tid - DH)]);

#pragma unroll
  for (int i = 0; i < 2; ++i) {
    *(f32x4*)(&xpb_A[0][i * 2048 + tid * 4]) = st_A[i];
    *(f32x4*)(&xpb_B[0][i * 2048 + tid * 4]) = st_B[i];
  }
#pragma unroll
  for (int i = 0; i < 2; ++i) {
    st_A[i] = *(const f32x4*)(outb_A + 4096 + i * 2048 + tid * 4);
    st_B[i] = *(const f32x4*)(outb_B + 4096 + i * 2048 + tid * 4);
  }
  __syncthreads();

  // A fragments (both batches): rows 1..15 zero, set ONCE; only l15==0 lanes
  // ever overwrite. Warm-up: read batch A's frags for step 0.
  short8 Af_A[8], Af_B[8];
#pragma unroll
  for (int kk = 0; kk < 8; ++kk) {
    Af_A[kk] = (short8){0, 0, 0, 0, 0, 0, 0, 0};
    Af_B[kk] = (short8){0, 0, 0, 0, 0, 0, 0, 0};
  }
  if (l15 == 0) {
#pragma unroll
    for (int kk = 0; kk < 8; ++kk)
      Af_A[kk] = *(const short8*)(hb_A + 32 * kk + koff);
  }

#define INTERVAL(C, O, tC, OBND, OCC) do {                                    \
    const int tc_ = (tC);                                                     \
    float xb_[2];                                                             \
    if (lane < 16) {                                                          \
      _Pragma("unroll")                                                       \
      for (int n = 0; n < 2; ++n)                                             \
        xb_[n] = xpb_##C[(tc_ >> 4) & 1][(tc_ & 15) * DH + 32 * w + 16 * n + lane]; \
    }                                                                         \
    if (l15 == 0) {                                                           \
      _Pragma("unroll")                                                       \
      for (int kk = 0; kk < 8; ++kk)                                          \
        Af_##O[kk] = *(const short8*)(hb_##O + 32 * kk + koff);               \
    }                                                                         \
    if (OBND) {                                                               \
      const int cc_ = (OCC);                                                  \
      const int nc_ = cc_ + 1;                                                \
      if (nc_ < NCHUNK) {                                                     \
        _Pragma("unroll")                                                     \
        for (int k = 0; k < 2; ++k)                                           \
          *(f32x4*)(&xpb_##O[nc_ & 1][k * 2048 + tid * 4]) = st_##O[k];       \
        const int pc_ = nc_ + 1;                                              \
        if (pc_ < NCHUNK) {                                                   \
          _Pragma("unroll")                                                   \
          for (int k = 0; k < 2; ++k)                                         \
            st_##O[k] = *(const f32x4*)(outb_##O + (size_t)pc_ * 4096 + k * 2048 + tid * 4); \
        }                                                                     \
      }                                                                       \
      f32x4 o0_ = *(const f32x4*)(&xout_##O[tid * 4]);                        \
      f32x4 o1_ = *(const f32x4*)(&xout_##O[2048 + tid * 4]);                 \
      *(f32x4*)(outb_##O + (size_t)cc_ * 4096 + tid * 4) = o0_;               \
      *(f32x4*)(outb_##O + (size_t)cc_ * 4096 + 2048 + tid * 4) = o1_;        \
    }                                                                         \
    __builtin_amdgcn_sched_barrier(0);                                        \
    f32x4 ac0_[2], ac1_[2];                                                   \
    _Pragma("unroll")                                                         \
    for (int n = 0; n < 2; ++n) {                                             \
      ac0_[n] = (f32x4){0.f, 0.f, 0.f, 0.f};                                  \
      ac1_[n] = (f32x4){0.f, 0.f, 0.f, 0.f};                                  \
    }                                                                         \
    _Pragma("unroll")                                                         \
    for (int kk = 0; kk < 4; ++kk)                                            \
      _Pragma("unroll")                                                       \
      for (int n = 0; n < 2; ++n)                                             \
        ac0_[n] = __builtin_amdgcn_mfma_f32_16x16x32_bf16(Af_##C[kk], Bf[n][kk], ac0_[n], 0, 0, 0); \
    _Pragma("unroll")                                                         \
    for (int kk = 4; kk < 8; ++kk)                                            \
      _Pragma("unroll")                                                       \
      for (int n = 0; n < 2; ++n)                                             \
        ac1_[n] = __builtin_amdgcn_mfma_f32_16x16x32_bf16(Af_##C[kk], Bf[n][kk], ac1_[n], 0, 0, 0); \
    if (lane < 16) {                                                          \
      float v_[2];                                                            \
      _Pragma("unroll")                                                       \
      for (int n = 0; n < 2; ++n) {                                           \
        v_[n] = (ac0_[n][0] + ac1_[n][0]) + xb_[n];                           \
        v_[n] = fmaxf(v_[n], 0.0f);                                           \
        hb_##C[32 * w + 16 * n + lane] = f2bf(v_[n]);                         \
      }                                                                       \
      _Pragma("unroll")                                                       \
      for (int n = 0; n < 2; ++n)                                             \
        xout_##C[(tc_ & 15) * DH + 32 * w + 16 * n + lane] = v_[n];           \
    }                                                                         \
    WG_BARRIER();                                                             \
  } while (0)

  for (int t = 0; t < T_LEN; ++t) {
    // Compute A step t; issue B's reads (B computes t next interval);
    // B finished step t-1 last interval -> B boundary at t%16==0 (t>0).
    INTERVAL(A, B, t, (t > 0 && (t & 15) == 0), (t >> 4) - 1);
    // Compute B step t; issue A's reads for step t+1;
    // A finished step t this iteration -> A boundary at t%16==15.
    INTERVAL(B, A, t, ((t & 15) == 15), (t >> 4));
  }

  // Final dump of B's last chunk (its boundary would fall at t==T_LEN).
  {
    const int cc = NCHUNK - 1;
    f32x4 o0 = *(const f32x4*)(&xout_B[tid * 4]);
    f32x4 o1 = *(const f32x4*)(&xout_B[2048 + tid * 4]);
    *(f32x4*)(outb_B + (size_t)cc * 4096 + tid * 4) = o0;
    *(f32x4*)(outb_B + (size_t)cc * 4096 + 2048 + tid * 4) = o1;
  }
#undef INTERVAL
}

extern "C" void kernel_launch(void* const* d_in, const int* in_sizes, int n_in,
                              void* d_out, int out_size, void* d_ws, size_t ws_size,
                              hipStream_t stream) {
  const float* x    = (const float*)d_in[0];
  const float* h0   = (const float*)d_in[1];
  const float* W_in = (const float*)d_in[2];
  const float* b_in = (const float*)d_in[3];
  const float* W_h  = (const float*)d_in[4];
  const float* b_h  = (const float*)d_in[5];
  float* out = (float*)d_out;

  hipLaunchKernelGGL(xproj_gemm, dim3(512), dim3(256), 0, stream, x, W_in, b_in, b_h, out);
  hipLaunchKernelGGL(rnn_scan, dim3(16), dim3(512), 0, stream, h0, W_h, out);
}

// Round 8
// 840.930 us; speedup vs baseline: 2.3295x; 2.3295x over previous
//
#include <hip/hip_runtime.h>

#define T_LEN 2048
#define DH 256
#define NCHUNK (T_LEN / 16)

typedef short short8 __attribute__((ext_vector_type(8)));
typedef float f32x4 __attribute__((ext_vector_type(4)));

__device__ __forceinline__ unsigned short f2bf(float f) {
  unsigned u = __builtin_bit_cast(unsigned, f);
  u += 0x7fffu + ((u >> 16) & 1u);   // round-to-nearest-even
  return (unsigned short)(u >> 16);
}

// Minimal step barrier: wait only this wave's outstanding LDS ops (the 2
// h-writes; all reads were already consumed), rendezvous, and fence the
// scheduler so next step's ds_reads can't hoist above the barrier.
// vmcnt deliberately NOT drained: xb prefetch loads + h stores stay in
// flight across steps (no cross-wave hazard goes through global memory).
#define STEP_BARRIER() do {                                 \
  asm volatile("s_waitcnt lgkmcnt(0)" ::: "memory");        \
  __builtin_amdgcn_s_barrier();                             \
  __builtin_amdgcn_sched_barrier(0);                        \
} while (0)

// ---------------------------------------------------------------------------
// Phase 1: out = x @ W_in + b_in + b_h (b_h folded). Grid 512 x 256 thr.
// MFMA 16x16x32 bf16. A[m][k]: m=lane&15, k=(lane>>4)*8+j; B same k, c=lane&15;
// D: c=lane&15, m=(lane>>4)*4+r.
// ---------------------------------------------------------------------------
__global__ __launch_bounds__(256, 1) void xproj_gemm(
    const float* __restrict__ x, const float* __restrict__ W_in,
    const float* __restrict__ b_in, const float* __restrict__ b_h,
    float* __restrict__ out) {
  const int tid  = threadIdx.x;
  const int lane = tid & 63;
  const int w    = tid >> 6;
  const int l15  = lane & 15;
  const int lg   = lane >> 4;
  const int koff = lg * 8;
  const int m0   = blockIdx.x * 128;

  short8 Bf[4][8];
#pragma unroll
  for (int n = 0; n < 4; ++n) {
    const int c = 64 * w + 16 * n + l15;
#pragma unroll
    for (int kk = 0; kk < 8; ++kk) {
      short8 bf;
#pragma unroll
      for (int j = 0; j < 8; ++j)
        bf[j] = (short)f2bf(W_in[(32 * kk + koff + j) * DH + c]);
      Bf[n][kk] = bf;
    }
  }
  float bin[4];
#pragma unroll
  for (int n = 0; n < 4; ++n) {
    const int c = 64 * w + 16 * n + l15;
    bin[n] = b_in[c] + b_h[c];
  }

  for (int slab = 0; slab < 8; ++slab) {
    const float* xr = x + (size_t)(m0 + slab * 16 + l15) * DH;
    short8 A[8];
#pragma unroll
    for (int kk = 0; kk < 8; ++kk) {
      f32x4 v0 = *(const f32x4*)(xr + 32 * kk + koff);
      f32x4 v1 = *(const f32x4*)(xr + 32 * kk + koff + 4);
      short8 a;
      a[0] = f2bf(v0[0]); a[1] = f2bf(v0[1]); a[2] = f2bf(v0[2]); a[3] = f2bf(v0[3]);
      a[4] = f2bf(v1[0]); a[5] = f2bf(v1[1]); a[6] = f2bf(v1[2]); a[7] = f2bf(v1[3]);
      A[kk] = a;
    }
    f32x4 acc[4];
#pragma unroll
    for (int n = 0; n < 4; ++n) acc[n] = (f32x4){0.f, 0.f, 0.f, 0.f};
#pragma unroll
    for (int kk = 0; kk < 8; ++kk)
#pragma unroll
      for (int n = 0; n < 4; ++n)
        acc[n] = __builtin_amdgcn_mfma_f32_16x16x32_bf16(A[kk], Bf[n][kk], acc[n], 0, 0, 0);
#pragma unroll
    for (int n = 0; n < 4; ++n) {
      const int c = 64 * w + 16 * n + l15;
#pragma unroll
      for (int r = 0; r < 4; ++r)
        out[(size_t)(m0 + slab * 16 + lg * 4 + r) * DH + c] = acc[n][r] + bin[n];
    }
  }
}

// ---------------------------------------------------------------------------
// Phase 2: serial scan. Grid 32 (one WG per batch) x 512 thr (8 waves).
// MINIMAL barrier interval — LDS carries ONLY the 512-byte h vector:
//   barrier -> 8 exec-masked ds_read_b128 (A-frag) -> 16 MFMA -> epilogue
//   (+xb from REGISTERS, relu, 2 ds_write_b16 h, 2 global stores) -> barrier.
// x_proj lives in per-lane registers: each chunk of 16 steps needs 32 floats
// on lanes<16 (static-indexed via fully unrolled chunk body), double-buffered,
// loaded from global TWO chunks ahead so latency never surfaces. No xpb/xout
// LDS, no publish block, no extra boundary barriers: exactly one barrier per
// step, every interval identical.
// ---------------------------------------------------------------------------
__global__ __launch_bounds__(512, 2) void rnn_scan(
    const float* __restrict__ h0, const float* __restrict__ W_h,
    float* __restrict__ out) {
  __shared__ __align__(16) unsigned short hb[2][DH];

  const int tid  = threadIdx.x;
  const int lane = tid & 63;
  const int w    = tid >> 6;         // 0..7
  const int l15  = lane & 15;
  const int lg   = lane >> 4;
  const int koff = lg * 8;
  const int b    = blockIdx.x;
  float* outb = out + (size_t)b * T_LEN * DH;

  // xb chunk buffers (registers; all indices static after full unroll).
  float xbA[32], xbB[32];

  // Issue a chunk's 32 xb loads (lanes<16 only; cols 32w+l15 and +16).
  auto ISSUE_XB = [&](int cc, float (&xb)[32]) {
    if (cc < NCHUNK && lane < 16) {
      const float* p = outb + (size_t)cc * 16 * DH + 32 * w + l15;
#pragma unroll
      for (int s = 0; s < 16; ++s) {
        xb[2 * s]     = p[(size_t)s * DH];
        xb[2 * s + 1] = p[(size_t)s * DH + 16];
      }
    }
  };

  ISSUE_XB(0, xbA);   // fly under the W_h fragment load
  ISSUE_XB(1, xbB);

  // W_h bf16 fragments: wave w owns cols [32w, 32w+32) as 2 16-col tiles.
  short8 Bf[2][8];
#pragma unroll
  for (int n = 0; n < 2; ++n) {
    const int c = 32 * w + 16 * n + l15;
#pragma unroll
    for (int kk = 0; kk < 8; ++kk) {
      short8 bf;
#pragma unroll
      for (int j = 0; j < 8; ++j)
        bf[j] = (short)f2bf(W_h[(32 * kk + koff + j) * DH + c]);
      Bf[n][kk] = bf;
    }
  }

  if (tid < DH) hb[0][tid] = f2bf(h0[b * DH + tid]);
  __syncthreads();

  // A fragments: rows 1..15 zero, set ONCE; only l15==0 lanes overwrite.
  short8 A[8];
#pragma unroll
  for (int kk = 0; kk < 8; ++kk) A[kk] = (short8){0, 0, 0, 0, 0, 0, 0, 0};

  // One chunk = 16 fully-unrolled steps; at the end, refill this chunk's xb
  // buffer for chunk cc+2 (regs just freed; WAR safe by in-order issue).
  auto CHUNK = [&](int cc, float (&xb)[32]) {
    float* orow = outb + (size_t)cc * 16 * DH;
#pragma unroll
    for (int s = 0; s < 16; ++s) {
      const unsigned short* hbR = hb[s & 1];
      unsigned short* hbW = hb[(s + 1) & 1];
      if (l15 == 0) {
#pragma unroll
        for (int kk = 0; kk < 8; ++kk)
          A[kk] = *(const short8*)(hbR + 32 * kk + koff);
      }

      // 16 MFMAs: 2 col-tiles x 2 sub-accumulators of depth 4.
      f32x4 ac[2][2];
#pragma unroll
      for (int n = 0; n < 2; ++n) {
        ac[n][0] = (f32x4){0.f, 0.f, 0.f, 0.f};
        ac[n][1] = (f32x4){0.f, 0.f, 0.f, 0.f};
      }
#pragma unroll
      for (int kk = 0; kk < 4; ++kk)
#pragma unroll
        for (int n = 0; n < 2; ++n)
          ac[n][0] = __builtin_amdgcn_mfma_f32_16x16x32_bf16(A[kk], Bf[n][kk], ac[n][0], 0, 0, 0);
#pragma unroll
      for (int kk = 4; kk < 8; ++kk)
#pragma unroll
        for (int n = 0; n < 2; ++n)
          ac[n][1] = __builtin_amdgcn_mfma_f32_16x16x32_bf16(A[kk], Bf[n][kk], ac[n][1], 0, 0, 0);

      // Valid output row m=0 -> lanes 0..15, element 0. xb is a REGISTER.
      if (lane < 16) {
        float v0 = (ac[0][0][0] + ac[0][1][0]) + xb[2 * s];
        float v1 = (ac[1][0][0] + ac[1][1][0]) + xb[2 * s + 1];
        v0 = fmaxf(v0, 0.0f);
        v1 = fmaxf(v1, 0.0f);
        hbW[32 * w + lane]      = f2bf(v0);   // next step's critical dep
        hbW[32 * w + 16 + lane] = f2bf(v1);
        orow[(size_t)s * DH + 32 * w + lane]      = v0;  // fire-and-forget
        orow[(size_t)s * DH + 32 * w + 16 + lane] = v1;
      }
      STEP_BARRIER();
    }
    ISSUE_XB(cc + 2, xb);
  };

  for (int c2 = 0; c2 < NCHUNK; c2 += 2) {
    CHUNK(c2, xbA);
    CHUNK(c2 + 1, xbB);
  }
}

extern "C" void kernel_launch(void* const* d_in, const int* in_sizes, int n_in,
                              void* d_out, int out_size, void* d_ws, size_t ws_size,
                              hipStream_t stream) {
  const float* x    = (const float*)d_in[0];
  const float* h0   = (const float*)d_in[1];
  const float* W_in = (const float*)d_in[2];
  const float* b_in = (const float*)d_in[3];
  const float* W_h  = (const float*)d_in[4];
  const float* b_h  = (const float*)d_in[5];
  float* out = (float*)d_out;

  hipLaunchKernelGGL(xproj_gemm, dim3(512), dim3(256), 0, stream, x, W_in, b_in, b_h, out);
  hipLaunchKernelGGL(rnn_scan, dim3(32), dim3(512), 0, stream, h0, W_h, out);
}